// Round 15
// baseline (183.593 us; speedup 1.0000x reference)
//
#include <hip/hip_runtime.h>

#define CELL 50.0f
#define N_TABLE 1024
#define NB 1024            // buckets of 128 atoms each (max 131072 atoms)
#define NBLK 512           // histogram/scatter blocks
#define THREADS 256
#define SCAT_THREADS 512
#define LBUF_CAP 25088     // max entries per scatter block (2*ppb)
#define RED_THREADS 512
#define PHASE_CAP 9216     // entries sorted per reduce phase (36.9 KB LDS)

typedef unsigned int uint;
typedef unsigned long long ull;

// ---------------- K0: pack q into float4 ----------------
__global__ __launch_bounds__(THREADS) void pack_q4_kernel(
    const float* __restrict__ q, float4* __restrict__ q4, int n_atoms)
{
    int i = blockIdx.x * THREADS + threadIdx.x;
    if (i < n_atoms)
        q4[i] = make_float4(q[3 * i], q[3 * i + 1], q[3 * i + 2], 0.0f);
}

// ---------------- K1: per-block bucket histogram (int4 loads) ----------------
__global__ __launch_bounds__(THREADS) void hist_kernel(
    const int2* __restrict__ nbr, uint* __restrict__ partial,
    uint* __restrict__ rawh, int n_pairs, int ppb)
{
    __shared__ uint h[NB];
    for (int k = threadIdx.x; k < NB; k += THREADS) h[k] = 0;
    __syncthreads();
    int start = blockIdx.x * ppb;                 // ppb even -> start even
    int end   = min(start + ppb, n_pairs & ~1);
    const int4* nbr4 = (const int4*)nbr;
    for (int p2 = (start >> 1) + threadIdx.x; p2 < (end >> 1); p2 += THREADS) {
        int4 v = nbr4[p2];
        atomicAdd(&h[((uint)v.x) >> 7], 1u);
        atomicAdd(&h[((uint)v.y) >> 7], 1u);
        atomicAdd(&h[((uint)v.z) >> 7], 1u);
        atomicAdd(&h[((uint)v.w) >> 7], 1u);
    }
    if (blockIdx.x == 0 && threadIdx.x == 0 && (n_pairs & 1)) {
        int2 ij = nbr[n_pairs - 1];
        atomicAdd(&h[((uint)ij.x) >> 7], 1u);
        atomicAdd(&h[((uint)ij.y) >> 7], 1u);
    }
    __syncthreads();
    for (int k = threadIdx.x; k < NB; k += THREADS) {
        uint c = h[k];
        partial[k * NBLK + blockIdx.x] = c;
        rawh[blockIdx.x * NB + k]      = c;
    }
}

// ---------------- K2a: per-bucket exclusive scan over block partials ----------------
__global__ __launch_bounds__(THREADS) void scan_rows_kernel(
    uint* __restrict__ partial, uint* __restrict__ binTotal)
{
    __shared__ uint s[THREADS];
    int bin = blockIdx.x;
    uint running = 0;
    for (int c = 0; c < NBLK / THREADS; c++) {
        int idx = bin * NBLK + c * THREADS + threadIdx.x;
        uint v = partial[idx];
        s[threadIdx.x] = v;
        __syncthreads();
        for (int off = 1; off < THREADS; off <<= 1) {
            uint t = (threadIdx.x >= (uint)off) ? s[threadIdx.x - off] : 0u;
            __syncthreads();
            s[threadIdx.x] += t;
            __syncthreads();
        }
        partial[idx] = running + s[threadIdx.x] - v;   // exclusive within bin
        uint csum = s[THREADS - 1];
        __syncthreads();
        running += csum;
    }
    if (threadIdx.x == 0) binTotal[bin] = running;
}

// ---------------- K2b: exclusive scan of bucket totals ----------------
__global__ __launch_bounds__(THREADS) void scan_totals_kernel(
    const uint* __restrict__ binTotal, uint* __restrict__ binBase)
{
    __shared__ uint s[THREADS];
    uint v[4];
    uint sum = 0;
    int base = threadIdx.x * 4;
    for (int k = 0; k < 4; k++) { v[k] = binTotal[base + k]; sum += v[k]; }
    s[threadIdx.x] = sum;
    __syncthreads();
    for (int off = 1; off < THREADS; off <<= 1) {
        uint t = (threadIdx.x >= (uint)off) ? s[threadIdx.x - off] : 0u;
        __syncthreads();
        s[threadIdx.x] += t;
        __syncthreads();
    }
    uint run = s[threadIdx.x] - sum;
    for (int k = 0; k < 4; k++) { binBase[base + k] = run; run += v[k]; }
    if (threadIdx.x == THREADS - 1) binBase[NB] = run;
}

// ---------------- K3: LDS-sorted scatter (coalesced run writes) ----------------
__global__ __launch_bounds__(SCAT_THREADS) void scatter_sorted_kernel(
    const int2* __restrict__ nbr, const uint* __restrict__ rawh,
    const uint* __restrict__ partial, const uint* __restrict__ binBase,
    uint* __restrict__ entries, int n_pairs, int ppb)
{
    __shared__ uint lbuf[LBUF_CAP];          // 100.4 KB
    __shared__ uint localBase[NB];           // 4 KB
    __shared__ uint lcur[NB];                // 4 KB
    __shared__ uint gcur[NB];                // 4 KB: prefetched global dst bases
    __shared__ uint ssc[SCAT_THREADS];       // 2 KB

    int tid = threadIdx.x;
    int blk = blockIdx.x;

    // prefetch global copy-out bases early (latency amortized once, 512-wide)
    for (int k = tid; k < NB; k += SCAT_THREADS)
        gcur[k] = binBase[k] + partial[k * NBLK + blk];

    // per-block histogram -> exclusive scan (2 buckets per thread)
    uint v0 = rawh[blk * NB + 2 * tid];
    uint v1 = rawh[blk * NB + 2 * tid + 1];
    uint sum2 = v0 + v1;
    ssc[tid] = sum2;
    __syncthreads();
    for (int off = 1; off < SCAT_THREADS; off <<= 1) {
        uint t = (tid >= off) ? ssc[tid - off] : 0u;
        __syncthreads();
        ssc[tid] += t;
        __syncthreads();
    }
    uint base = ssc[tid] - sum2;
    localBase[2 * tid]     = base;      lcur[2 * tid]     = base;
    localBase[2 * tid + 1] = base + v0; lcur[2 * tid + 1] = base + v0;
    __syncthreads();

    // bin entries into LDS (double-buffered loads, batched atomics)
    int start = blk * ppb;
    int end   = min(start + ppb, n_pairs & ~1);
    const int4* nbr4 = (const int4*)nbr;
    int lim = end >> 1;
    int p2  = (start >> 1) + tid;
    if (p2 < lim) {
        int4 v = nbr4[p2];
        for (;;) {
            int pn = p2 + SCAT_THREADS;
            int4 vnext;
            bool has = pn < lim;
            if (has) vnext = nbr4[pn];
            uint i0 = (uint)v.x, j0 = (uint)v.y, i1 = (uint)v.z, j1 = (uint)v.w;
            uint o0 = atomicAdd(&lcur[i0 >> 7], 1u);
            uint o1 = atomicAdd(&lcur[j0 >> 7], 1u);
            uint o2 = atomicAdd(&lcur[i1 >> 7], 1u);
            uint o3 = atomicAdd(&lcur[j1 >> 7], 1u);
            lbuf[o0] = (j0 << 7) | (i0 & 127u);
            lbuf[o1] = (i0 << 7) | (j0 & 127u);
            lbuf[o2] = (j1 << 7) | (i1 & 127u);
            lbuf[o3] = (i1 << 7) | (j1 & 127u);
            if (!has) break;
            v = vnext; p2 = pn;
        }
    }
    if (blk == 0 && tid == 0 && (n_pairs & 1)) {
        int2 ij = nbr[n_pairs - 1];
        uint i = (uint)ij.x, j = (uint)ij.y;
        uint o;
        o = atomicAdd(&lcur[i >> 7], 1u); lbuf[o] = (j << 7) | (i & 127u);
        o = atomicAdd(&lcur[j >> 7], 1u); lbuf[o] = (i << 7) | (j & 127u);
    }
    __syncthreads();

    // wave-per-bucket coalesced copy-out (gcur from LDS, no serial L2 reads)
    int wave = tid >> 6, lane = tid & 63;
    for (int b = wave; b < NB; b += SCAT_THREADS / 64) {
        uint lb  = localBase[b];
        uint cnt = lcur[b] - lb;
        if (!cnt) continue;
        uint gdst = gcur[b];
        for (uint o = lane; o < cnt; o += 64)
            entries[gdst + o] = lbuf[lb + o];
    }
}

// ---------------- K3-fallback: unsorted scatter (if LBUF too small) ----------------
__global__ __launch_bounds__(THREADS) void scatter_plain_kernel(
    const int2* __restrict__ nbr, const uint* __restrict__ partial,
    const uint* __restrict__ binBase, uint* __restrict__ entries,
    int n_pairs, int ppb)
{
    __shared__ uint cur[NB];
    for (int k = threadIdx.x; k < NB; k += THREADS)
        cur[k] = binBase[k] + partial[k * NBLK + blockIdx.x];
    __syncthreads();
    int start = blockIdx.x * ppb;
    int end   = min(start + ppb, n_pairs & ~1);
    const int4* nbr4 = (const int4*)nbr;
    for (int p2 = (start >> 1) + threadIdx.x; p2 < (end >> 1); p2 += THREADS) {
        int4 v = nbr4[p2];
        uint i0 = (uint)v.x, j0 = (uint)v.y, i1 = (uint)v.z, j1 = (uint)v.w;
        uint p;
        p = atomicAdd(&cur[i0 >> 7], 1u); entries[p] = (j0 << 7) | (i0 & 127u);
        p = atomicAdd(&cur[j0 >> 7], 1u); entries[p] = (i0 << 7) | (j0 & 127u);
        p = atomicAdd(&cur[i1 >> 7], 1u); entries[p] = (j1 << 7) | (i1 & 127u);
        p = atomicAdd(&cur[j1 >> 7], 1u); entries[p] = (i1 << 7) | (j1 & 127u);
    }
    if (blockIdx.x == 0 && threadIdx.x == 0 && (n_pairs & 1)) {
        int2 ij = nbr[n_pairs - 1];
        uint i = (uint)ij.x, j = (uint)ij.y;
        uint p;
        p = atomicAdd(&cur[i >> 7], 1u); entries[p] = (j << 7) | (i & 127u);
        p = atomicAdd(&cur[j >> 7], 1u); entries[p] = (i << 7) | (j & 127u);
    }
}

// ---------------- physics (shared by reduce paths) ----------------
__device__ __forceinline__ void phys_acc(
    float ax, float ay, float az, float ox, float oy, float oz,
    const float* __restrict__ tfa, const float* __restrict__ tfd,
    float r0, float inv_dr, float& fx, float& fy, float& fz)
{
    float dx = ax - ox, dy = ay - oy, dz = az - oz;
    // exact minimum image for d in (-50,50): round-half-even boundary at +/-25.0
    dx -= (dx > 25.0f) ? 50.0f : ((dx < -25.0f) ? -50.0f : 0.0f);
    dy -= (dy > 25.0f) ? 50.0f : ((dy < -25.0f) ? -50.0f : 0.0f);
    dz -= (dz > 25.0f) ? 50.0f : ((dz < -25.0f) ? -50.0f : 0.0f);
    float r2 = dx * dx + dy * dy + dz * dz;
    float rs = __builtin_amdgcn_rsqf(fmaxf(r2, 1e-24f));   // ~1ulp v_rsq_f32
    float r  = r2 * rs;                                    // r = sqrt(r2)
    float t  = (r - r0) * inv_dr;
    t = fminf(fmaxf(t, 0.0f), 1023.0f);
    int idx = min((int)t, N_TABLE - 2);
    float frac = t - (float)idx;
    float sm = (tfa[idx] + frac * tfd[idx]) * rs;          // fm / r
    fx += sm * dx; fy += sm * dy; fz += sm * dz;
}

// ---------------- K4: per-bucket reduce via in-LDS counting sort ----------------
// Per phase (<=PHASE_CAP entries): histogram locals -> scan -> sort `other` into
// LDS -> thread t owns atom (t&127), quarter (t>>7): register accumulation over
// its contiguous run. No ballots, no shfl loops, no atomics in the hot loop.
template<int USE_Q4>
__global__ __launch_bounds__(RED_THREADS) void reduce_sorted_kernel(
    const float* __restrict__ q, const float4* __restrict__ q4,
    const float* __restrict__ table_r, const float* __restrict__ table_f,
    const uint* __restrict__ binBase, const uint* __restrict__ entries,
    float* __restrict__ force, int n_atoms)
{
    __shared__ float tfa[N_TABLE];            // 4 KB
    __shared__ float tfd[N_TABLE];            // 4 KB
    __shared__ uint  sorted[PHASE_CAP];       // 36.9 KB
    __shared__ uint  hcnt[128], hcur[128], hstart[128], sscan[128];  // 2 KB
    __shared__ float paccx[RED_THREADS], paccy[RED_THREADS], paccz[RED_THREADS]; // 6 KB

    int b = blockIdx.x, tid = threadIdx.x;
    int atomBase = b << 7;
    if (atomBase >= n_atoms) return;
    int nA = min(128, n_atoms - atomBase);

    const float r0     = table_r[0];
    const float rend   = table_r[N_TABLE - 1];
    const float inv_dr = (float)(N_TABLE - 1) / (rend - r0);

    for (int k = tid; k < N_TABLE - 1; k += RED_THREADS) {
        float a = table_f[k];
        tfa[k] = a; tfd[k] = table_f[k + 1] - a;
    }
    paccx[tid] = 0.0f; paccy[tid] = 0.0f; paccz[tid] = 0.0f;

    // this thread's atom position (loop-invariant across all phases)
    int a = tid & 127, s4 = tid >> 7;
    float ax = 0.0f, ay = 0.0f, az = 0.0f;
    if (a < nA) {
        if (USE_Q4) { float4 v = q4[atomBase + a]; ax = v.x; ay = v.y; az = v.z; }
        else {
            ax = q[(atomBase + a) * 3];
            ay = q[(atomBase + a) * 3 + 1];
            az = q[(atomBase + a) * 3 + 2];
        }
    }

    uint e0 = binBase[b], e1 = binBase[b + 1];

    for (uint es = e0; es < e1; es += PHASE_CAP) {
        uint ee = min(es + PHASE_CAP, e1);

        if (tid < 128) hcnt[tid] = 0;
        __syncthreads();

        // phase histogram of locals (coalesced read; ~40 distinct addrs/wave)
        for (uint e = es + tid; e < ee; e += RED_THREADS)
            atomicAdd(&hcnt[entries[e] & 127u], 1u);
        __syncthreads();

        // 128-wide exclusive scan
        if (tid < 128) sscan[tid] = hcnt[tid];
        __syncthreads();
        for (int off = 1; off < 128; off <<= 1) {
            uint t = 0;
            if (tid < 128 && tid >= off) t = sscan[tid - off];
            __syncthreads();
            if (tid < 128) sscan[tid] += t;
            __syncthreads();
        }
        if (tid < 128) {
            uint s0 = sscan[tid] - hcnt[tid];
            hstart[tid] = s0; hcur[tid] = s0;
        }
        __syncthreads();

        // counting sort: store `other` at sorted position
        for (uint e = es + tid; e < ee; e += RED_THREADS) {
            uint ev = entries[e];
            uint p  = atomicAdd(&hcur[ev & 127u], 1u);
            sorted[p] = ev >> 7;
        }
        __syncthreads();

        // register-accumulating processing over this thread's run quarter
        {
            uint st  = hstart[a];
            uint cnt = hcnt[a];
            uint chunk = (cnt + 3) >> 2;
            uint k0 = min((uint)s4 * chunk, cnt);
            uint k1 = min(k0 + chunk, cnt);
            float fx = 0.0f, fy = 0.0f, fz = 0.0f;

            uint k = k0;
            for (; k + 4 <= k1; k += 4) {
                uint o0 = sorted[st + k],     o1 = sorted[st + k + 1];
                uint o2 = sorted[st + k + 2], o3 = sorted[st + k + 3];
                float x0, y0, z0, x1, y1, z1, x2, y2, z2, x3, y3, z3;
                if (USE_Q4) {
                    float4 g0 = q4[o0], g1 = q4[o1], g2 = q4[o2], g3 = q4[o3];
                    x0 = g0.x; y0 = g0.y; z0 = g0.z;
                    x1 = g1.x; y1 = g1.y; z1 = g1.z;
                    x2 = g2.x; y2 = g2.y; z2 = g2.z;
                    x3 = g3.x; y3 = g3.y; z3 = g3.z;
                } else {
                    x0 = q[3*o0]; y0 = q[3*o0+1]; z0 = q[3*o0+2];
                    x1 = q[3*o1]; y1 = q[3*o1+1]; z1 = q[3*o1+2];
                    x2 = q[3*o2]; y2 = q[3*o2+1]; z2 = q[3*o2+2];
                    x3 = q[3*o3]; y3 = q[3*o3+1]; z3 = q[3*o3+2];
                }
                phys_acc(ax, ay, az, x0, y0, z0, tfa, tfd, r0, inv_dr, fx, fy, fz);
                phys_acc(ax, ay, az, x1, y1, z1, tfa, tfd, r0, inv_dr, fx, fy, fz);
                phys_acc(ax, ay, az, x2, y2, z2, tfa, tfd, r0, inv_dr, fx, fy, fz);
                phys_acc(ax, ay, az, x3, y3, z3, tfa, tfd, r0, inv_dr, fx, fy, fz);
            }
            for (; k < k1; ++k) {
                uint o = sorted[st + k];
                float ox, oy, oz;
                if (USE_Q4) { float4 g = q4[o]; ox = g.x; oy = g.y; oz = g.z; }
                else { ox = q[3*o]; oy = q[3*o+1]; oz = q[3*o+2]; }
                phys_acc(ax, ay, az, ox, oy, oz, tfa, tfd, r0, inv_dr, fx, fy, fz);
            }
            paccx[tid] += fx; paccy[tid] += fy; paccz[tid] += fz;
        }
        __syncthreads();   // protect hcnt/sorted before next phase
    }

    // combine the 4 quarters and write
    for (int k = tid; k < nA; k += RED_THREADS) {
        float sx = paccx[k] + paccx[k + 128] + paccx[k + 256] + paccx[k + 384];
        float sy = paccy[k] + paccy[k + 128] + paccy[k + 256] + paccy[k + 384];
        float sz = paccz[k] + paccz[k + 128] + paccz[k + 256] + paccz[k + 384];
        force[(atomBase + k) * 3 + 0] = sx;
        force[(atomBase + k) * 3 + 1] = sy;
        force[(atomBase + k) * 3 + 2] = sz;
    }
}

// ---------------- fallback: proven global-atomic kernel ----------------
__global__ __launch_bounds__(THREADS) void pair_force_atomic_kernel(
    const float* __restrict__ q, const int2* __restrict__ nbr,
    const float* __restrict__ table_r, const float* __restrict__ table_f,
    float* __restrict__ force, int n_pairs)
{
    __shared__ float tr[N_TABLE];
    __shared__ float tf[N_TABLE];
    for (int k = threadIdx.x; k < N_TABLE; k += THREADS) { tr[k] = table_r[k]; tf[k] = table_f[k]; }
    __syncthreads();
    const float r0 = tr[0], rend = tr[N_TABLE - 1];
    const float inv_dr = (float)(N_TABLE - 1) / (rend - r0);
    int p = blockIdx.x * THREADS + threadIdx.x;
    if (p >= n_pairs) return;
    int2 ij = nbr[p];
    int i = ij.x, j = ij.y;
    float dx = q[3 * i] - q[3 * j], dy = q[3 * i + 1] - q[3 * j + 1], dz = q[3 * i + 2] - q[3 * j + 2];
    dx -= CELL * rintf(dx / CELL); dy -= CELL * rintf(dy / CELL); dz -= CELL * rintf(dz / CELL);
    float r = sqrtf(dx * dx + dy * dy + dz * dz);
    float inv = 1.0f / fmaxf(r, 1e-12f);
    float fm;
    if (r <= r0) fm = tf[0];
    else if (r >= rend) fm = tf[N_TABLE - 1];
    else {
        float t = (r - r0) * inv_dr;
        int idx = min(max((int)t, 0), N_TABLE - 2);
        if (r < tr[idx]) idx = max(idx - 1, 0);
        else if (r >= tr[idx + 1]) idx = min(idx + 1, N_TABLE - 2);
        float rl = tr[idx], rh = tr[idx + 1];
        fm = tf[idx] + (r - rl) * (tf[idx + 1] - tf[idx]) / (rh - rl);
    }
    float s = fm * inv;
    float fx = s * dx, fy = s * dy, fz = s * dz;
    atomicAdd(&force[3 * i + 0], fx); atomicAdd(&force[3 * i + 1], fy); atomicAdd(&force[3 * i + 2], fz);
    atomicAdd(&force[3 * j + 0], -fx); atomicAdd(&force[3 * j + 1], -fy); atomicAdd(&force[3 * j + 2], -fz);
}

extern "C" void kernel_launch(void* const* d_in, const int* in_sizes, int n_in,
                              void* d_out, int out_size, void* d_ws, size_t ws_size,
                              hipStream_t stream) {
    const float* q       = (const float*)d_in[0];
    const int2*  nbr     = (const int2*)d_in[1];
    const float* table_r = (const float*)d_in[2];
    const float* table_f = (const float*)d_in[3];
    float*       force   = (float*)d_out;

    const int n_pairs = in_sizes[1] / 2;
    const int n_atoms = in_sizes[0] / 3;

    // workspace layout (256B-aligned)
    size_t off_partial  = 0;
    size_t off_rawh     = (off_partial + (size_t)NB * NBLK * 4 + 255) & ~255ull;   // 2 MB
    size_t off_binTotal = (off_rawh + (size_t)NB * NBLK * 4 + 255) & ~255ull;      // +2 MB
    size_t off_binBase  = (off_binTotal + (size_t)NB * 4 + 255) & ~255ull;
    size_t off_entries  = (off_binBase + (size_t)(NB + 1) * 4 + 255) & ~255ull;
    size_t off_q4       = (off_entries + (size_t)2 * n_pairs * 4 + 255) & ~255ull;
    size_t need_base    = off_q4;                       // without q4
    size_t need_q4      = off_q4 + (size_t)n_atoms * 16;

    if (ws_size < need_base || n_atoms > NB * 128) {
        hipMemsetAsync(d_out, 0, (size_t)out_size * sizeof(float), stream);
        int blocks = (n_pairs + THREADS - 1) / THREADS;
        pair_force_atomic_kernel<<<blocks, THREADS, 0, stream>>>(q, nbr, table_r, table_f, force, n_pairs);
        return;
    }

    char* ws = (char*)d_ws;
    uint*   partial  = (uint*)(ws + off_partial);
    uint*   rawh     = (uint*)(ws + off_rawh);
    uint*   binTotal = (uint*)(ws + off_binTotal);
    uint*   binBase  = (uint*)(ws + off_binBase);
    uint*   entries  = (uint*)(ws + off_entries);
    float4* q4       = (float4*)(ws + off_q4);
    int use_q4 = (ws_size >= need_q4) ? 1 : 0;

    int ppb = (((n_pairs + NBLK - 1) / NBLK) + 1) & ~1;   // even pairs per block

    if (use_q4) {
        int pb = (n_atoms + THREADS - 1) / THREADS;
        pack_q4_kernel<<<pb, THREADS, 0, stream>>>(q, q4, n_atoms);
    }
    hist_kernel<<<NBLK, THREADS, 0, stream>>>(nbr, partial, rawh, n_pairs, ppb);
    scan_rows_kernel<<<NB, THREADS, 0, stream>>>(partial, binTotal);
    scan_totals_kernel<<<1, THREADS, 0, stream>>>(binTotal, binBase);
    if (2 * ppb <= LBUF_CAP)
        scatter_sorted_kernel<<<NBLK, SCAT_THREADS, 0, stream>>>(
            nbr, rawh, partial, binBase, entries, n_pairs, ppb);
    else
        scatter_plain_kernel<<<NBLK, THREADS, 0, stream>>>(
            nbr, partial, binBase, entries, n_pairs, ppb);
    if (use_q4)
        reduce_sorted_kernel<1><<<NB, RED_THREADS, 0, stream>>>(q, q4, table_r, table_f, binBase, entries, force, n_atoms);
    else
        reduce_sorted_kernel<0><<<NB, RED_THREADS, 0, stream>>>(q, q4, table_r, table_f, binBase, entries, force, n_atoms);
}